// Round 13
// baseline (17.696 us; speedup 1.0000x reference)
//
#include <hip/hip_runtime.h>

#define NPTS 8192
#define G 4096                      // buckets per plane
#define LOF (-6.0f)
#define BWF (12.0f / (float)G)      // bucket width
#define INVW ((float)G / 12.0f)
#define BTHREADS 1024
#define VPT (NPTS / BTHREADS)       // 8 values per build thread
#define QTHREADS 256
#define QBLKS (6 * NPTS / QTHREADS) // 192
#define KWIN 16                     // initial one-sided window (positions)
#define KEXP 32                     // expansion step (positions)

// ws float layout: sorted[6][NPTS] | start[6][G+1] | partials[QBLKS] | counter
#define WS_SORTED 0
#define WS_START  (6 * NPTS)
#define WS_PART   (WS_START + 6 * (G + 1))
#define WS_CNT    (WS_PART + QBLKS)

__device__ __forceinline__ int bucket_of(float v) {
    int b = (int)((v - LOF) * INVW);
    return min(max(b, 0), G - 1);
}

// K1: one block per plane (6 x 1024). Counting-sort the plane's 8192 values
// into global CSR (sorted + start) via LDS hist -> shfl scan -> LDS scatter ->
// coalesced float4 writeback. Block 0 zeroes the finisher counter.
__global__ __launch_bounds__(BTHREADS) void build_kernel(
    const float* __restrict__ pred, const float* __restrict__ target,
    float* __restrict__ sorted, int* __restrict__ start,
    unsigned int* __restrict__ counter)
{
    const int p   = blockIdx.x;       // 0..5
    const int arr = p / 3, ch = p - arr * 3;
    const float* src = arr ? target : pred;

    __shared__ unsigned hist[G];      // 16 KB
    __shared__ unsigned curs[G];      // 16 KB
    __shared__ __align__(16) float sv[NPTS];  // 32 KB sorted stage
    __shared__ unsigned wtot[BTHREADS / 64];

    const int t = threadIdx.x, lane = t & 63, wave = t >> 6;

    float v[VPT];
    #pragma unroll
    for (int j = 0; j < VPT; ++j)
        v[j] = src[(t + j * BTHREADS) * 3 + ch];

    #pragma unroll
    for (int i = t; i < G; i += BTHREADS) hist[i] = 0u;
    __syncthreads();

    #pragma unroll
    for (int j = 0; j < VPT; ++j)
        atomicAdd(&hist[bucket_of(v[j])], 1u);
    __syncthreads();

    // exclusive scan over G bins; 4 bins/thread
    const int BPT = G / BTHREADS;
    unsigned cnt[BPT], tsum = 0;
    #pragma unroll
    for (int j = 0; j < BPT; ++j) { cnt[j] = hist[t * BPT + j]; tsum += cnt[j]; }

    unsigned inc = tsum;
    #pragma unroll
    for (int off = 1; off < 64; off <<= 1) {
        unsigned n = __shfl_up(inc, off, 64);
        if (lane >= off) inc += n;
    }
    if (lane == 63) wtot[wave] = inc;
    __syncthreads();
    unsigned woff = 0;
    for (int w = 0; w < wave; ++w) woff += wtot[w];
    unsigned run = woff + (inc - tsum);

    #pragma unroll
    for (int j = 0; j < BPT; ++j) {
        curs[t * BPT + j] = run;
        start[p * (G + 1) + t * BPT + j] = (int)run;
        run += cnt[j];
    }
    if (t == 0) {
        start[p * (G + 1) + G] = NPTS;
        if (p == 0) *counter = 0u;    // fresh every call: replay/poison-safe
    }
    __syncthreads();

    #pragma unroll
    for (int j = 0; j < VPT; ++j) {
        const unsigned pos = atomicAdd(&curs[bucket_of(v[j])], 1u);
        sv[pos] = v[j];               // intra-bucket order irrelevant (exact min)
    }
    __syncthreads();

    for (int i = t; i < NPTS / 4; i += BTHREADS)
        ((float4*)(sorted + p * NPTS))[i] = ((const float4*)sv)[i];
}

// K2: 192 blocks x 256 thr; queries taken from the SORTED array (sum is
// order-free), so adjacent lanes have adjacent values -> each block's
// candidate window traffic is a ~4 KB contiguous L1-resident strip of
// sorted[cp]; expansion branches are wave-coherent. No LDS staging.
// Exact: position-window scan + bucket-edge stop bounds (proven R8-R12).
// Last-done block (counter protocol, proven R8) reduces 192 partials -> out.
__global__ __launch_bounds__(QTHREADS) void query_kernel(
    const float* __restrict__ sorted, const int* __restrict__ start,
    float* __restrict__ partials, unsigned int* __restrict__ counter,
    float* __restrict__ out)
{
    const int t = threadIdx.x;
    const int b = blockIdx.x;
    const int qp = b >> 5, s = b & 31;          // query plane, slice
    const int cp = (qp + 3) % 6;                // candidate plane

    const float x = sorted[qp * NPTS + s * QTHREADS + t];   // coalesced
    const int*   st = start + cp * (G + 1);
    const float* cs = sorted + cp * NPTS;

    const int bx = bucket_of(x);
    const int p0 = st[bx], p1 = st[bx + 1];     // adjacent lanes: L1 broadcast

    int lo = max(p0 - KWIN, 0) & ~3;
    int hi = min(p1 + KWIN, NPTS);
    hi = (hi + 3) & ~3;

    const float4* c4 = (const float4*)cs;
    float m0 = 3.0e38f, m1 = 3.0e38f;
    for (int k = lo >> 2; k < (hi >> 2); ++k) {
        const float4 c = c4[k];                 // L1-hit, independent
        m0 = fminf(m0, fminf(fabsf(x - c.x), fabsf(x - c.y)));
        m1 = fminf(m1, fminf(fabsf(x - c.z), fabsf(x - c.w)));
    }
    float m = fminf(m0, m1);

    // unscanned-lower values < upper edge of bucket(cs[lo]);
    // unscanned-higher values >= lower edge of bucket(cs[hi-1]).
    float bl = (lo == 0)    ? 3.0e38f
             : x - (LOF + (float)(bucket_of(cs[lo]) + 1) * BWF);
    float br = (hi >= NPTS) ? 3.0e38f
             : (LOF + (float)bucket_of(cs[hi - 1]) * BWF) - x;

    while (m > fminf(bl, br)) {                 // rare; wave-coherent
        if (bl <= br) {
            const int nlo = max(lo - KEXP, 0);
            for (int k = nlo >> 2; k < (lo >> 2); ++k) {
                const float4 c = c4[k];
                m = fminf(m, fminf(fminf(fabsf(x - c.x), fabsf(x - c.y)),
                                   fminf(fabsf(x - c.z), fabsf(x - c.w))));
            }
            lo = nlo;
            bl = (lo == 0) ? 3.0e38f
               : x - (LOF + (float)(bucket_of(cs[lo]) + 1) * BWF);
        } else {
            const int nhi = min(hi + KEXP, NPTS);
            for (int k = hi >> 2; k < (nhi >> 2); ++k) {
                const float4 c = c4[k];
                m = fminf(m, fminf(fminf(fabsf(x - c.x), fabsf(x - c.y)),
                                   fminf(fabsf(x - c.z), fabsf(x - c.w))));
            }
            hi = nhi;
            br = (hi >= NPTS) ? 3.0e38f
               : (LOF + (float)bucket_of(cs[hi - 1]) * BWF) - x;
        }
    }

    // block sum (2 waves -> 4 waves worth handled generically)
    float sum = m;
    #pragma unroll
    for (int off = 32; off > 0; off >>= 1)
        sum += __shfl_down(sum, off, 64);
    __shared__ float wsum[QTHREADS / 64];
    __shared__ int isfin;
    if ((t & 63) == 0) wsum[t >> 6] = sum;
    __syncthreads();

    if (t == 0) {
        float psum = 0.f;
        #pragma unroll
        for (int w = 0; w < QTHREADS / 64; ++w) psum += wsum[w];
        atomicExch(&partials[b], psum);         // device-visible
        __threadfence();
        isfin = (atomicAdd(counter, 1u) == QBLKS - 1);
    }
    __syncthreads();

    if (isfin) {
        __threadfence();
        float sfin = (t < QBLKS) ? atomicAdd(&partials[t], 0.0f) : 0.f;
        #pragma unroll
        for (int off = 32; off > 0; off >>= 1)
            sfin += __shfl_down(sfin, off, 64);
        if ((t & 63) == 0) wsum[t >> 6] = sfin;
        __syncthreads();
        if (t == 0) {
            float tot = 0.f;
            #pragma unroll
            for (int w = 0; w < QTHREADS / 64; ++w) tot += wsum[w];
            out[0] = tot * (1.0f / NPTS);
        }
    }
}

extern "C" void kernel_launch(void* const* d_in, const int* in_sizes, int n_in,
                              void* d_out, int out_size, void* d_ws, size_t ws_size,
                              hipStream_t stream) {
    const float* pred   = (const float*)d_in[0];
    const float* target = (const float*)d_in[1];
    float* out = (float*)d_out;
    float* wsf = (float*)d_ws;

    float*        sorted   = wsf + WS_SORTED;
    int*          startp   = (int*)(wsf + WS_START);
    float*        partials = wsf + WS_PART;
    unsigned int* counter  = (unsigned int*)(wsf + WS_CNT);

    build_kernel<<<6, BTHREADS, 0, stream>>>(pred, target, sorted, startp, counter);
    query_kernel<<<QBLKS, QTHREADS, 0, stream>>>(sorted, startp, partials, counter, out);
}

// Round 14
// 13.020 us; speedup vs baseline: 1.3592x; 1.3592x over previous
//
#include <hip/hip_runtime.h>

#define NPTS 8192
#define G 4096                      // buckets per plane
#define LOF (-6.0f)
#define BWF (12.0f / (float)G)      // bucket width
#define INVW ((float)G / 12.0f)
#define THREADS 1024
#define VPT (NPTS / THREADS)        // 8 candidates per thread
#define BPT (G / THREADS)           // 4 bins per thread (scan)
#define QPB 256                     // queries per block
#define NSLICE (NPTS / QPB)         // 32 slices per plane
#define NBLK (6 * NSLICE)           // 192 blocks
#define KWIN 16                     // initial one-sided window (positions)
#define KEXP 32                     // expansion step (positions)

__device__ __forceinline__ int bucket_of(float v) {
    int b = (int)((v - LOF) * INVW);
    return min(max(b, 0), G - 1);
}

// Fused kernel: block = (plane p, slice s of 256 queries). The block
// counting-sorts plane p's 8192 values into LDS (hist -> shfl scan ->
// in-place-cursor scatter), then 256 of its 1024 threads answer one query
// each from LDS. Build is replicated per block (free: blocks < CUs); query
// phase is 4 waves -> light LDS contention. Exact: position-window scan +
// content-based bucket-edge stop bounds (proven R8-R13, any scatter order).
__global__ __launch_bounds__(THREADS) void chamfer_fused_kernel(
    const float* __restrict__ pred, const float* __restrict__ target,
    float* __restrict__ partials)
{
    const int b = blockIdx.x;
    const int p = b >> 5, s = b & (NSLICE - 1);
    const int arr = p / 3, ch = p - arr * 3;
    const float* csrc = arr ? target : pred;   // candidates: this plane
    const float* qsrc = arr ? pred   : target; // queries: other array

    __shared__ unsigned hist[G + 1];          // counts -> starts -> cursors
    __shared__ __align__(16) float sv[NPTS];  // bucket-sorted values (32 KB)
    __shared__ unsigned wtot[THREADS / 64];
    __shared__ float    wsum[THREADS / 64];

    const int t = threadIdx.x, lane = t & 63, wave = t >> 6;

    // Early loads (overlap with hist zeroing).
    float x = 0.f;
    if (t < QPB) x = qsrc[(s * QPB + t) * 3 + ch];

    float v[VPT];
    #pragma unroll
    for (int j = 0; j < VPT; ++j)
        v[j] = csrc[(t + j * THREADS) * 3 + ch];

    #pragma unroll
    for (int i = t; i < G; i += THREADS) hist[i] = 0u;
    __syncthreads();

    #pragma unroll
    for (int j = 0; j < VPT; ++j)
        atomicAdd(&hist[bucket_of(v[j])], 1u);
    __syncthreads();

    // Exclusive scan over G bins (4 bins/thread; shfl in-wave, LDS across).
    unsigned cnt[BPT], tsum = 0;
    #pragma unroll
    for (int j = 0; j < BPT; ++j) { cnt[j] = hist[t * BPT + j]; tsum += cnt[j]; }

    unsigned inc = tsum;
    #pragma unroll
    for (int off = 1; off < 64; off <<= 1) {
        unsigned n = __shfl_up(inc, off, 64);
        if (lane >= off) inc += n;
    }
    if (lane == 63) wtot[wave] = inc;
    __syncthreads();
    unsigned woff = 0;
    for (int w = 0; w < wave; ++w) woff += wtot[w];
    unsigned run = woff + (inc - tsum);

    #pragma unroll
    for (int j = 0; j < BPT; ++j) {       // own bins: race-free
        hist[t * BPT + j] = run;          // counts -> exclusive starts
        run += cnt[j];
    }
    if (t == 0) hist[G] = NPTS;
    __syncthreads();

    // Snapshot this query's CSR range into registers BEFORE the scatter
    // destroys the starts (in-place cursors).
    int bx = 0, p0 = 0, p1 = 0;
    if (t < QPB) {
        bx = bucket_of(x);
        p0 = (int)hist[bx];
        p1 = (int)hist[bx + 1];
    }
    __syncthreads();

    #pragma unroll
    for (int j = 0; j < VPT; ++j) {
        const unsigned pos = atomicAdd(&hist[bucket_of(v[j])], 1u);
        sv[pos] = v[j];                   // intra-bucket order irrelevant (min)
    }
    __syncthreads();

    // ---- query from LDS (4 waves only) ----
    float m = 0.f;                        // non-query threads contribute 0
    if (t < QPB) {
        int lo = max(p0 - KWIN, 0) & ~3;
        int hi = min(p1 + KWIN, NPTS);
        hi = (hi + 3) & ~3;

        const float4* c4 = (const float4*)sv;
        float m0 = 3.0e38f, m1 = 3.0e38f;
        for (int k = lo >> 2; k < (hi >> 2); ++k) {
            const float4 c = c4[k];
            m0 = fminf(m0, fminf(fabsf(x - c.x), fabsf(x - c.y)));
            m1 = fminf(m1, fminf(fabsf(x - c.z), fabsf(x - c.w)));
        }
        m = fminf(m0, m1);

        // unscanned-lower values < upper edge of bucket(sv[lo]);
        // unscanned-higher values >= lower edge of bucket(sv[hi-1]).
        float bl = (lo == 0)    ? 3.0e38f
                 : x - (LOF + (float)(bucket_of(sv[lo]) + 1) * BWF);
        float br = (hi >= NPTS) ? 3.0e38f
                 : (LOF + (float)bucket_of(sv[hi - 1]) * BWF) - x;

        while (m > fminf(bl, br)) {       // rare; LDS-cheap
            if (bl <= br) {
                const int nlo = max(lo - KEXP, 0);
                for (int k = nlo >> 2; k < (lo >> 2); ++k) {
                    const float4 c = c4[k];
                    m = fminf(m, fminf(fminf(fabsf(x - c.x), fabsf(x - c.y)),
                                       fminf(fabsf(x - c.z), fabsf(x - c.w))));
                }
                lo = nlo;
                bl = (lo == 0) ? 3.0e38f
                   : x - (LOF + (float)(bucket_of(sv[lo]) + 1) * BWF);
            } else {
                const int nhi = min(hi + KEXP, NPTS);
                for (int k = hi >> 2; k < (nhi >> 2); ++k) {
                    const float4 c = c4[k];
                    m = fminf(m, fminf(fminf(fabsf(x - c.x), fabsf(x - c.y)),
                                       fminf(fabsf(x - c.z), fabsf(x - c.w))));
                }
                hi = nhi;
                br = (hi >= NPTS) ? 3.0e38f
                   : (LOF + (float)bucket_of(sv[hi - 1]) * BWF) - x;
            }
        }
    }

    // block sum (fixed order -> deterministic), plain store
    float sum = m;
    #pragma unroll
    for (int off = 32; off > 0; off >>= 1)
        sum += __shfl_down(sum, off, 64);
    if (lane == 0) wsum[wave] = sum;
    __syncthreads();
    if (t == 0) {
        float tot = 0.f;
        #pragma unroll
        for (int w = 0; w < THREADS / 64; ++w) tot += wsum[w];
        partials[b] = tot;
    }
}

// Final: one wave sums the 192 block-partials -> out = sum / NPTS.
__global__ __launch_bounds__(64) void final_kernel(
    const float* __restrict__ partials, float* __restrict__ out)
{
    const int t = threadIdx.x;
    float sf = partials[t] + partials[t + 64] + partials[t + 128];
    #pragma unroll
    for (int off = 32; off > 0; off >>= 1)
        sf += __shfl_down(sf, off, 64);
    if (t == 0) out[0] = sf * (1.0f / NPTS);
}

extern "C" void kernel_launch(void* const* d_in, const int* in_sizes, int n_in,
                              void* d_out, int out_size, void* d_ws, size_t ws_size,
                              hipStream_t stream) {
    const float* pred   = (const float*)d_in[0];
    const float* target = (const float*)d_in[1];
    float* out = (float*)d_out;
    float* partials = (float*)d_ws;   // [NBLK]

    chamfer_fused_kernel<<<NBLK, THREADS, 0, stream>>>(pred, target, partials);
    final_kernel<<<1, 64, 0, stream>>>(partials, out);
}